// Round 1
// baseline (1342.110 us; speedup 1.0000x reference)
//
#include <hip/hip_runtime.h>

typedef unsigned short u16;
typedef short bf16x8 __attribute__((ext_vector_type(8)));   // MFMA A/B frag (8 bf16)
typedef float f32x4  __attribute__((ext_vector_type(4)));   // MFMA C/D frag
typedef u16   u16x8  __attribute__((ext_vector_type(8)));   // 16B vector ld/st

#define MFMA_BF16(a, b, c) __builtin_amdgcn_mfma_f32_16x16x32_bf16((a), (b), (c), 0, 0, 0)

#define B_  8
#define L_  2500
#define LP  2528          // L padded to 79*32
#define E_  100
#define F_  50
#define Y_  8922
#define YP  8960          // Y padded to 70*128 (=280*32)
#define KT_ 280           // K tiles of 32 over YP
#define NT_ 416           // N = B*F = 400 padded to 26*16

__device__ __forceinline__ u16 f2bf(float f) {
    unsigned int x = __float_as_uint(f);
    unsigned int r = x + 0x7fffu + ((x >> 16) & 1u);   // RNE
    return (u16)(r >> 16);
}

// ---------------------------------------------------------------- detector
__global__ void k0_detect(const int* __restrict__ x, int* __restrict__ flag) {
    if (threadIdx.x == 0) {
        int nz = 0;
        #pragma unroll
        for (int i = 0; i < 32; i++) nz |= x[2 * i + 1];
        *flag = (nz == 0) ? 1 : 0;   // all-high-words-zero => int64 buffer
    }
}

// ---------------------------------------------------------------- conv
// hp  : bf16 [B][LP][64]  (f<50 real, 50..63 zero)
// hpT : bf16 [B][64][LP]  (row 50 = 1.0 for l<2500 else 0; rows 51..63 zero)
__global__ __launch_bounds__(256) void k1_conv(
    const int* __restrict__ x, const int* __restrict__ flag,
    const float* __restrict__ embed_w, const float* __restrict__ conv_w,
    const float* __restrict__ conv_b,
    u16* __restrict__ hp, u16* __restrict__ hpT)
{
    __shared__ float sEmb[72 * 104];   // 72 rows (64 + 8 halo), stride 104 (16B aligned, low-conflict)
    __shared__ int   sId[72];
    const int tid = threadIdx.x;
    const int b  = blockIdx.y;
    const int l0 = blockIdx.x * 64;
    const int is64 = *flag;

    if (tid < 72) {
        int l = l0 - 4 + tid;
        int id = -1;
        if (l >= 0 && l < L_) id = is64 ? x[(b * L_ + l) * 2] : x[b * L_ + l];
        sId[tid] = id;
    }
    __syncthreads();
    for (int i = tid; i < 72 * 100; i += 256) {
        int r = i / 100, e = i - r * 100;
        int id = sId[r];
        sEmb[r * 104 + e] = (id >= 0) ? embed_w[(size_t)id * 100 + e] : 0.f;
    }
    __syncthreads();

    const int li = tid & 63;
    const int fg = __builtin_amdgcn_readfirstlane(tid >> 6);   // wave-uniform f-group 0..3

    float acc[13];
    #pragma unroll
    for (int i = 0; i < 13; i++) { int f = fg + 4 * i; acc[i] = (f < F_) ? conv_b[f] : 0.f; }

    for (int k = 0; k < 9; k++) {
        for (int e4 = 0; e4 < 25; e4++) {
            float4 h = *(const float4*)&sEmb[(li + k) * 104 + e4 * 4];
            #pragma unroll
            for (int i = 0; i < 13; i++) {
                int f = fg + 4 * i;
                if (f < F_) {
                    const float* wp = conv_w + (f * 100 + e4 * 4) * 9 + k;   // [F][E][K]
                    acc[i] += h.x * wp[0] + h.y * wp[9] + h.z * wp[18] + h.w * wp[27];
                }
            }
        }
    }

    int l = l0 + li;
    if (l < LP) {
        bool valid = (l < L_);
        #pragma unroll
        for (int i = 0; i < 13; i++) {
            int f = fg + 4 * i;
            if (f < F_) {
                u16 hv = 0;
                if (valid) {
                    float e2 = __expf(2.f * acc[i]);
                    hv = f2bf((e2 - 1.f) / (e2 + 1.f));   // tanh
                }
                hp [((size_t)b * LP + l) * 64 + f] = hv;
                hpT[((size_t)b * 64 + f) * LP + l] = hv;
            }
        }
        #pragma unroll
        for (int j = 0; j < 4; j++) {
            int f = 50 + fg + 4 * j;
            if (f < 64) {
                hp [((size_t)b * LP + l) * 64 + f] = 0;
                hpT[((size_t)b * 64 + f) * LP + l] = (f == 50 && valid) ? f2bf(1.f) : (u16)0;
            }
        }
    }
}

// ---------------------------------------------------------------- flash attention
// m4t : fp32 [B][Y][50]
__global__ __launch_bounds__(256) void k2_attn(
    const float* __restrict__ U4_w,
    const u16* __restrict__ hp, const u16* __restrict__ hpT,
    float* __restrict__ m4t)
{
    __shared__ u16  sU4[128 * 72];   // [y][f] f-contig, rows padded 72 (144B)
    __shared__ u16  sHp[32 * 72];    // [l][f] f-contig (S-GEMM B)
    __shared__ u16  sHt[64 * 40];    // [f][l] l-contig (PV B), rows padded 40 (80B)
    __shared__ u16  sP [128 * 40];   // [y][l] l-contig (PV A)
    __shared__ float sDen[128];

    const int tid  = threadIdx.x;
    const int b    = blockIdx.y;
    const int y0   = blockIdx.x * 128;
    const int w    = tid >> 6;
    const int lane = tid & 63;
    const int l15  = lane & 15;
    const int quad = lane >> 4;

    for (int i = tid; i < 128 * 72; i += 256) {
        int r = i / 72, c = i - r * 72;
        float v = 0.f;
        int y = y0 + r;
        if (c < F_ && y < Y_) v = U4_w[y * F_ + c];
        sU4[i] = f2bf(v);
    }
    __syncthreads();

    bf16x8 fa[2][2];   // hoisted U4 A-frags: A[m=lane&15][k=quad*8+j]
    #pragma unroll
    for (int mi = 0; mi < 2; mi++)
        #pragma unroll
        for (int ks = 0; ks < 2; ks++)
            fa[mi][ks] = *(const bf16x8*)&sU4[(w * 32 + mi * 16 + l15) * 72 + ks * 32 + quad * 8];

    const f32x4 fz = {0.f, 0.f, 0.f, 0.f};
    f32x4 pacc[2][4];
    #pragma unroll
    for (int mi = 0; mi < 2; mi++)
        #pragma unroll
        for (int ni = 0; ni < 4; ni++) pacc[mi][ni] = fz;

    for (int lt = 0; lt < 79; lt++) {
        const int l0 = lt * 32;
        __syncthreads();
        {   // stage hp tile [32][64->72] and hpT tile [64][32->40]
            int r = tid >> 3, seg = tid & 7;
            u16x8 v = *(const u16x8*)&hp[((size_t)b * LP + l0 + r) * 64 + seg * 8];
            *(u16x8*)&sHp[r * 72 + seg * 8] = v;
            int fr = tid >> 2, s2 = tid & 3;
            u16x8 v2 = *(const u16x8*)&hpT[((size_t)b * 64 + fr) * LP + l0 + s2 * 8];
            *(u16x8*)&sHt[fr * 40 + s2 * 8] = v2;
        }
        __syncthreads();

        // S = U4p [y×64f] · hp^T [64f×l]
        f32x4 sacc[2][2];
        #pragma unroll
        for (int mi = 0; mi < 2; mi++)
            #pragma unroll
            for (int ni = 0; ni < 2; ni++) sacc[mi][ni] = fz;
        #pragma unroll
        for (int ks = 0; ks < 2; ks++) {
            #pragma unroll
            for (int ni = 0; ni < 2; ni++) {
                bf16x8 fb = *(const bf16x8*)&sHp[(ni * 16 + l15) * 72 + ks * 32 + quad * 8];
                #pragma unroll
                for (int mi = 0; mi < 2; mi++)
                    sacc[mi][ni] = MFMA_BF16(fa[mi][ks], fb, sacc[mi][ni]);
            }
        }
        // P = exp(S) (no-max softmax: |s| bounded), write to LDS in A-layout
        #pragma unroll
        for (int mi = 0; mi < 2; mi++)
            #pragma unroll
            for (int ni = 0; ni < 2; ni++) {
                int lcol = ni * 16 + l15;
                bool lv = (l0 + lcol) < L_;
                #pragma unroll
                for (int r = 0; r < 4; r++) {
                    float p = lv ? __expf(sacc[mi][ni][r]) : 0.f;
                    sP[(w * 32 + mi * 16 + quad * 4 + r) * 40 + lcol] = f2bf(p);
                }
            }
        __syncthreads();

        // O += P [y×32l] · hp [32l×64f]   (col 50 of hpT row block = ones => denominator)
        bf16x8 fv[4];
        #pragma unroll
        for (int ni = 0; ni < 4; ni++)
            fv[ni] = *(const bf16x8*)&sHt[(ni * 16 + l15) * 40 + quad * 8];
        #pragma unroll
        for (int mi = 0; mi < 2; mi++) {
            bf16x8 fp_ = *(const bf16x8*)&sP[(w * 32 + mi * 16 + l15) * 40 + quad * 8];
            #pragma unroll
            for (int ni = 0; ni < 4; ni++)
                pacc[mi][ni] = MFMA_BF16(fp_, fv[ni], pacc[mi][ni]);
        }
    }

    // denominator column: f=50 -> ni=3, lane&15==2
    if (l15 == 2) {
        #pragma unroll
        for (int mi = 0; mi < 2; mi++)
            #pragma unroll
            for (int r = 0; r < 4; r++)
                sDen[w * 32 + mi * 16 + quad * 4 + r] = pacc[mi][3][r];
    }
    __syncthreads();

    #pragma unroll
    for (int mi = 0; mi < 2; mi++)
        #pragma unroll
        for (int ni = 0; ni < 4; ni++) {
            int f = ni * 16 + l15;
            if (f < F_) {
                #pragma unroll
                for (int r = 0; r < 4; r++) {
                    int yl = w * 32 + mi * 16 + quad * 4 + r;
                    int y = y0 + yl;
                    if (y < Y_)
                        m4t[((size_t)b * Y_ + y) * F_ + f] = pacc[mi][ni][r] / sDen[yl];
                }
            }
        }
}

// ---------------------------------------------------------------- support + y4t
// Bt : bf16 [KT_][NT_][32]  (z-tiled, n = b*50+g;  pads pre-zeroed by memset)
__global__ __launch_bounds__(256) void k3_support(
    const float* __restrict__ m4t, const float* __restrict__ gcn_w,
    const float* __restrict__ f4t_w, const float* __restrict__ f4t_b,
    u16* __restrict__ Bt, float* __restrict__ y4t_out)
{
    __shared__ float sW[50 * 52];   // gcn_w^T : [g][f], rows padded 52
    const int tid = threadIdx.x;
    for (int i = tid; i < 50 * 52; i += 256) {
        int g = i / 52, f = i - g * 52;
        sW[i] = (f < F_) ? gcn_w[f * F_ + g] : 0.f;
    }
    __syncthreads();

    const int b = blockIdx.y;
    const int y = blockIdx.x * 256 + tid;
    if (y >= Y_) return;

    float2 m[25];
    const float* mrow = m4t + ((size_t)b * Y_ + y) * F_;
    #pragma unroll
    for (int i = 0; i < 25; i++) m[i] = *(const float2*)(mrow + 2 * i);

    const int kt = y >> 5, zo = y & 31;
    u16* brow = Bt + (size_t)kt * (NT_ * 32) + (size_t)(b * F_) * 32 + zo;
    for (int g = 0; g < F_; g++) {
        float s = 0.f;
        const float* wr = sW + g * 52;
        #pragma unroll
        for (int i = 0; i < 25; i++) {
            float2 wv = *(const float2*)(wr + 2 * i);
            s += m[i].x * wv.x + m[i].y * wv.y;
        }
        brow[g * 32] = f2bf(s);
    }

    const float* tw = f4t_w + (size_t)y * F_;
    float acc = f4t_b[y];
    #pragma unroll
    for (int i = 0; i < 25; i++) {
        float2 wv = *(const float2*)(tw + 2 * i);
        acc += m[i].x * wv.x + m[i].y * wv.y;
    }
    y4t_out[(size_t)b * Y_ + y] = acc;
}

// ---------------------------------------------------------------- adj GEMM (the big one)
// out_part : fp32 [4][Y_][400]
__global__ __launch_bounds__(512) void k4_gemm(
    const float* __restrict__ adj, const u16* __restrict__ Bt,
    float* __restrict__ outp)
{
    __shared__ u16 sA[128 * 40];   // adj tile  [m][k], rows padded 40 (80B, 16B-aligned)
    __shared__ u16 sB[NT_ * 40];   // support tile [n][k]
    const int tid  = threadIdx.x;
    const int m0   = blockIdx.x * 128;
    const int kp   = blockIdx.y;
    const int w    = tid >> 6;
    const int lane = tid & 63;
    const int l15  = lane & 15;
    const int quad = lane >> 4;
    const int wm   = w & 3;    // M sub-block (0..3) -> rows wm*32..+32
    const int wn   = w >> 1 >> 1;  // N half (0..1) -> cols wn*208..+208

    const f32x4 fz = {0.f, 0.f, 0.f, 0.f};
    f32x4 acc[2][13];
    #pragma unroll
    for (int mi = 0; mi < 2; mi++)
        #pragma unroll
        for (int ni = 0; ni < 13; ni++) acc[mi][ni] = fz;

    for (int it = 0; it < 70; it++) {
        const int kt = kp * 70 + it;
        const int k0 = kt * 32;
        __syncthreads();
        {   // stage A: 128 rows x 32 cols fp32 -> bf16
            int r = tid >> 2, q = tid & 3;
            int y = m0 + r;
            int c0 = k0 + q * 8;
            float v[8];
            if (y < Y_ && c0 + 7 < Y_) {
                const float* src = adj + (size_t)y * Y_ + c0;
                float2 a0 = *(const float2*)(src);
                float2 a1 = *(const float2*)(src + 2);
                float2 a2 = *(const float2*)(src + 4);
                float2 a3 = *(const float2*)(src + 6);
                v[0] = a0.x; v[1] = a0.y; v[2] = a1.x; v[3] = a1.y;
                v[4] = a2.x; v[5] = a2.y; v[6] = a3.x; v[7] = a3.y;
            } else if (y < Y_) {
                #pragma unroll
                for (int j = 0; j < 8; j++)
                    v[j] = (c0 + j < Y_) ? adj[(size_t)y * Y_ + c0 + j] : 0.f;
            } else {
                #pragma unroll
                for (int j = 0; j < 8; j++) v[j] = 0.f;
            }
            u16x8 vv;
            #pragma unroll
            for (int j = 0; j < 8; j++) vv[j] = f2bf(v[j]);
            *(u16x8*)&sA[r * 40 + q * 8] = vv;
        }
        {   // stage B: contiguous 26624B tile -> padded rows
            const u16* bsrc = Bt + (size_t)kt * (NT_ * 32);
            #pragma unroll
            for (int it2 = 0; it2 < 4; it2++) {
                int idx = it2 * 512 + tid;
                if (idx < (NT_ * 32) / 8) {
                    u16x8 v = *(const u16x8*)&bsrc[idx * 8];
                    int n = idx >> 2, ko = (idx & 3) * 8;
                    *(u16x8*)&sB[n * 40 + ko] = v;
                }
            }
        }
        __syncthreads();

        bf16x8 fa_[2];
        #pragma unroll
        for (int mi = 0; mi < 2; mi++)
            fa_[mi] = *(const bf16x8*)&sA[(wm * 32 + mi * 16 + l15) * 40 + quad * 8];
        #pragma unroll
        for (int ni = 0; ni < 13; ni++) {
            bf16x8 fb = *(const bf16x8*)&sB[(wn * 208 + ni * 16 + l15) * 40 + quad * 8];
            acc[0][ni] = MFMA_BF16(fa_[0], fb, acc[0][ni]);
            acc[1][ni] = MFMA_BF16(fa_[1], fb, acc[1][ni]);
        }
    }

    float* dst = outp + (size_t)kp * Y_ * 400;
    #pragma unroll
    for (int mi = 0; mi < 2; mi++)
        #pragma unroll
        for (int ni = 0; ni < 13; ni++) {
            int n = wn * 208 + ni * 16 + l15;
            if (n < 400) {
                #pragma unroll
                for (int r = 0; r < 4; r++) {
                    int y = m0 + wm * 32 + mi * 16 + quad * 4 + r;
                    if (y < Y_) dst[(size_t)y * 400 + n] = acc[mi][ni][r];
                }
            }
        }
}

// ---------------------------------------------------------------- final y4
__global__ __launch_bounds__(256) void k5_final(
    const float* __restrict__ outp, const float* __restrict__ m4t,
    const float* __restrict__ gcn_b, const float* __restrict__ f4_w,
    const float* __restrict__ f4_b, float* __restrict__ y4_out)
{
    const int b = blockIdx.y;
    const int y = blockIdx.x * 256 + threadIdx.x;
    if (y >= Y_) return;

    const size_t PS = (size_t)Y_ * 400;
    const float* p0 = outp + (size_t)y * 400 + b * F_;
    const float* fw = f4_w + (size_t)y * 100;
    const float* mrow = m4t + ((size_t)b * Y_ + y) * F_;

    float acc = f4_b[y];
    #pragma unroll
    for (int i = 0; i < 25; i++) {
        float2 mv = *(const float2*)(mrow + 2 * i);
        float2 wv = *(const float2*)(fw + 2 * i);
        acc += mv.x * wv.x + mv.y * wv.y;
    }
    #pragma unroll
    for (int i = 0; i < 25; i++) {
        float sx = 0.f, sy = 0.f;
        #pragma unroll
        for (int kp = 0; kp < 4; kp++) {
            float2 v = *(const float2*)(p0 + kp * PS + 2 * i);
            sx += v.x; sy += v.y;
        }
        float2 gb = *(const float2*)(gcn_b + 2 * i);
        sx += gb.x; sy += gb.y;
        sx = sx > 0.f ? sx : 0.2f * sx;   // leaky_relu
        sy = sy > 0.f ? sy : 0.2f * sy;
        float2 wv = *(const float2*)(fw + 50 + 2 * i);
        acc += sx * wv.x + sy * wv.y;
    }
    y4_out[(size_t)b * Y_ + y] = acc;
}

// ---------------------------------------------------------------- launch
extern "C" void kernel_launch(void* const* d_in, const int* in_sizes, int n_in,
                              void* d_out, int out_size, void* d_ws, size_t ws_size,
                              hipStream_t stream) {
    const int*   x       = (const int*)d_in[0];
    const float* embed_w = (const float*)d_in[2];
    const float* conv_w  = (const float*)d_in[3];
    const float* conv_b  = (const float*)d_in[4];
    const float* U4_w    = (const float*)d_in[5];
    const float* gcn_w   = (const float*)d_in[6];
    const float* gcn_b   = (const float*)d_in[7];
    const float* adj     = (const float*)d_in[8];
    const float* f4t_w   = (const float*)d_in[9];
    const float* f4t_b   = (const float*)d_in[10];
    const float* f4_w    = (const float*)d_in[11];
    const float* f4_b    = (const float*)d_in[12];
    float* out = (float*)d_out;

    char* ws = (char*)d_ws;
    const size_t SZ_HP  = (size_t)B_ * LP * 64 * 2;          // 2,588,672
    const size_t SZ_BT  = (size_t)KT_ * NT_ * 32 * 2;        // 7,454,720
    const size_t SZ_M4T = (size_t)B_ * Y_ * F_ * 4;          // 14,275,200
    int*   flag = (int*)ws;
    u16*   hp   = (u16*)(ws + 16);
    u16*   hpT  = (u16*)(ws + 16 + SZ_HP);
    u16*   Bt   = (u16*)(ws + 16 + 2 * SZ_HP);
    float* m4t  = (float*)(ws + 16 + 2 * SZ_HP + SZ_BT);
    float* outp = (float*)(ws + 16 + 2 * SZ_HP + SZ_BT + SZ_M4T);   // 4*Y*400*4 = 57,100,800

    k0_detect<<<1, 64, 0, stream>>>(x, flag);
    k1_conv<<<dim3(40, 8), 256, 0, stream>>>(x, flag, embed_w, conv_w, conv_b, hp, hpT);
    hipMemsetAsync(Bt, 0, SZ_BT, stream);
    k2_attn<<<dim3(70, 8), 256, 0, stream>>>(U4_w, hp, hpT, m4t);
    k3_support<<<dim3(35, 8), 256, 0, stream>>>(m4t, gcn_w, f4t_w, f4t_b, Bt, out);
    k4_gemm<<<dim3(70, 4), 512, 0, stream>>>(adj, Bt, outp);
    k5_final<<<dim3(35, 8), 256, 0, stream>>>(outp, m4t, gcn_b, f4_w, f4_b,
                                              out + (size_t)B_ * Y_);
}

// Round 2
// 1114.344 us; speedup vs baseline: 1.2044x; 1.2044x over previous
//
#include <hip/hip_runtime.h>

typedef unsigned short u16;
typedef short bf16x8 __attribute__((ext_vector_type(8)));   // MFMA A/B frag (8 bf16)
typedef float f32x4  __attribute__((ext_vector_type(4)));   // MFMA C/D frag
typedef u16   u16x8  __attribute__((ext_vector_type(8)));   // 16B vector ld/st

#define MFMA_BF16(a, b, c) __builtin_amdgcn_mfma_f32_16x16x32_bf16((a), (b), (c), 0, 0, 0)

#define B_  8
#define L_  2500
#define LP  2528          // L padded to 79*32
#define E_  100
#define F_  50
#define Y_  8922
#define YP  8960          // Y padded to 70*128 (=280*32)
#define KT_ 280           // K tiles of 32 over YP
#define NT_ 416           // N = B*F = 400 padded to 26*16

__device__ __forceinline__ u16 f2bf(float f) {
    unsigned int x = __float_as_uint(f);
    unsigned int r = x + 0x7fffu + ((x >> 16) & 1u);   // RNE
    return (u16)(r >> 16);
}

// ---------------------------------------------------------------- prep
// wT : fp32 [9][50][100]  (conv_w transposed so conv staging is coalesced)
// also detects int64-vs-int32 x buffer
__global__ __launch_bounds__(256) void k0_prep(
    const int* __restrict__ x, const float* __restrict__ conv_w,
    int* __restrict__ flag, float* __restrict__ wT)
{
    const int k = blockIdx.x;           // 0..8
    const int tid = threadIdx.x;
    if (k == 0 && tid == 0) {
        int nz = 0;
        #pragma unroll
        for (int i = 0; i < 32; i++) nz |= x[2 * i + 1];
        *flag = (nz == 0) ? 1 : 0;      // all-high-words-zero => int64 buffer
    }
    for (int j = tid; j < 5000; j += 256)           // j = f*100 + e
        wT[k * 5000 + j] = conv_w[j * 9 + k];
}

// ---------------------------------------------------------------- conv (fp32, LDS-staged weights)
// hp  : bf16 [B][LP][64]  (f<50 real, 50..63 zero)
// hpT : bf16 [B][64][LP]  (row 50 = 1.0 for l<2500 else 0; rows 51..63 zero)
__global__ __launch_bounds__(256) void k1_conv(
    const int* __restrict__ x, const int* __restrict__ flag,
    const float* __restrict__ embed_w, const float* __restrict__ wT,
    const float* __restrict__ conv_b,
    u16* __restrict__ hp, u16* __restrict__ hpT)
{
    __shared__ float sEmb[72 * 104];   // 72 rows (64 + 8 halo), stride 104
    __shared__ float sW[50 * 104];     // per-k weight slice [f][e], stride 104
    __shared__ int   sId[72];
    const int tid = threadIdx.x;
    const int b  = blockIdx.y;
    const int l0 = blockIdx.x * 64;
    const int is64 = *flag;

    if (tid < 72) {
        int l = l0 - 4 + tid;
        int id = -1;
        if (l >= 0 && l < L_) id = is64 ? x[(b * L_ + l) * 2] : x[b * L_ + l];
        sId[tid] = id;
    }
    __syncthreads();
    for (int i = tid; i < 72 * 25; i += 256) {       // float4 granules
        int r = i / 25, e4 = i - r * 25;
        int id = sId[r];
        float4 v = make_float4(0.f, 0.f, 0.f, 0.f);
        if (id >= 0) v = *(const float4*)&embed_w[(size_t)id * 100 + e4 * 4];
        *(float4*)&sEmb[r * 104 + e4 * 4] = v;
    }

    const int li = tid & 63;
    const int fg = __builtin_amdgcn_readfirstlane(tid >> 6);   // wave-uniform f-group 0..3

    float acc[13];
    #pragma unroll
    for (int i = 0; i < 13; i++) { int f = fg + 4 * i; acc[i] = (f < F_) ? conv_b[f] : 0.f; }

    for (int k = 0; k < 9; k++) {
        __syncthreads();   // previous iter's sW reads done (also orders emb staging at k=0)
        for (int i = tid; i < 1250; i += 256) {      // stage wT[k] : 50 f x 25 float4
            int f = i / 25, e4 = i - f * 25;
            *(float4*)&sW[f * 104 + e4 * 4] = *(const float4*)&wT[k * 5000 + f * 100 + e4 * 4];
        }
        __syncthreads();
        for (int e4 = 0; e4 < 25; e4++) {
            float4 h = *(const float4*)&sEmb[(li + k) * 104 + e4 * 4];
            #pragma unroll
            for (int i = 0; i < 13; i++) {
                int f = fg + 4 * i;
                if (f < F_) {
                    float4 w = *(const float4*)&sW[f * 104 + e4 * 4];   // uniform -> LDS broadcast
                    acc[i] += h.x * w.x + h.y * w.y + h.z * w.z + h.w * w.w;
                }
            }
        }
    }

    int l = l0 + li;
    if (l < LP) {
        bool valid = (l < L_);
        #pragma unroll
        for (int i = 0; i < 13; i++) {
            int f = fg + 4 * i;
            if (f < F_) {
                u16 hv = 0;
                if (valid) {
                    float e2 = __expf(2.f * acc[i]);
                    hv = f2bf((e2 - 1.f) / (e2 + 1.f));   // tanh
                }
                hp [((size_t)b * LP + l) * 64 + f] = hv;
                hpT[((size_t)b * 64 + f) * LP + l] = hv;
            }
        }
        #pragma unroll
        for (int j = 0; j < 4; j++) {
            int f = 50 + fg + 4 * j;
            if (f < 64) {
                hp [((size_t)b * LP + l) * 64 + f] = 0;
                hpT[((size_t)b * 64 + f) * LP + l] = (f == 50 && valid) ? f2bf(1.f) : (u16)0;
            }
        }
    }
}

// ---------------------------------------------------------------- flash attention
// m4t : fp32 [B][Y][50]
__global__ __launch_bounds__(256) void k2_attn(
    const float* __restrict__ U4_w,
    const u16* __restrict__ hp, const u16* __restrict__ hpT,
    float* __restrict__ m4t)
{
    __shared__ u16  sU4[128 * 72];   // [y][f] f-contig, rows padded 72 (144B)
    __shared__ u16  sHp[32 * 72];    // [l][f] f-contig (S-GEMM B)
    __shared__ u16  sHt[64 * 40];    // [f][l] l-contig (PV B), rows padded 40 (80B)
    __shared__ u16  sP [128 * 40];   // [y][l] l-contig (PV A)
    __shared__ float sDen[128];

    const int tid  = threadIdx.x;
    const int b    = blockIdx.y;
    const int y0   = blockIdx.x * 128;
    const int w    = tid >> 6;
    const int lane = tid & 63;
    const int l15  = lane & 15;
    const int quad = lane >> 4;

    for (int i = tid; i < 128 * 72; i += 256) {
        int r = i / 72, c = i - r * 72;
        float v = 0.f;
        int y = y0 + r;
        if (c < F_ && y < Y_) v = U4_w[y * F_ + c];
        sU4[i] = f2bf(v);
    }
    __syncthreads();

    bf16x8 fa[2][2];   // hoisted U4 A-frags: A[m=lane&15][k=quad*8+j]
    #pragma unroll
    for (int mi = 0; mi < 2; mi++)
        #pragma unroll
        for (int ks = 0; ks < 2; ks++)
            fa[mi][ks] = *(const bf16x8*)&sU4[(w * 32 + mi * 16 + l15) * 72 + ks * 32 + quad * 8];

    const f32x4 fz = {0.f, 0.f, 0.f, 0.f};
    f32x4 pacc[2][4];
    #pragma unroll
    for (int mi = 0; mi < 2; mi++)
        #pragma unroll
        for (int ni = 0; ni < 4; ni++) pacc[mi][ni] = fz;

    for (int lt = 0; lt < 79; lt++) {
        const int l0 = lt * 32;
        __syncthreads();
        {   // stage hp tile [32][64->72] and hpT tile [64][32->40]
            int r = tid >> 3, seg = tid & 7;
            u16x8 v = *(const u16x8*)&hp[((size_t)b * LP + l0 + r) * 64 + seg * 8];
            *(u16x8*)&sHp[r * 72 + seg * 8] = v;
            int fr = tid >> 2, s2 = tid & 3;
            u16x8 v2 = *(const u16x8*)&hpT[((size_t)b * 64 + fr) * LP + l0 + s2 * 8];
            *(u16x8*)&sHt[fr * 40 + s2 * 8] = v2;
        }
        __syncthreads();

        // S = U4p [y×64f] · hp^T [64f×l]
        f32x4 sacc[2][2];
        #pragma unroll
        for (int mi = 0; mi < 2; mi++)
            #pragma unroll
            for (int ni = 0; ni < 2; ni++) sacc[mi][ni] = fz;
        #pragma unroll
        for (int ks = 0; ks < 2; ks++) {
            #pragma unroll
            for (int ni = 0; ni < 2; ni++) {
                bf16x8 fb = *(const bf16x8*)&sHp[(ni * 16 + l15) * 72 + ks * 32 + quad * 8];
                #pragma unroll
                for (int mi = 0; mi < 2; mi++)
                    sacc[mi][ni] = MFMA_BF16(fa[mi][ks], fb, sacc[mi][ni]);
            }
        }
        // P = exp(S) (no-max softmax: |s| bounded), write to LDS in A-layout
        #pragma unroll
        for (int mi = 0; mi < 2; mi++)
            #pragma unroll
            for (int ni = 0; ni < 2; ni++) {
                int lcol = ni * 16 + l15;
                bool lv = (l0 + lcol) < L_;
                #pragma unroll
                for (int r = 0; r < 4; r++) {
                    float p = lv ? __expf(sacc[mi][ni][r]) : 0.f;
                    sP[(w * 32 + mi * 16 + quad * 4 + r) * 40 + lcol] = f2bf(p);
                }
            }
        __syncthreads();

        // O += P [y×32l] · hp [32l×64f]   (col 50 of hpT row block = ones => denominator)
        bf16x8 fv[4];
        #pragma unroll
        for (int ni = 0; ni < 4; ni++)
            fv[ni] = *(const bf16x8*)&sHt[(ni * 16 + l15) * 40 + quad * 8];
        #pragma unroll
        for (int mi = 0; mi < 2; mi++) {
            bf16x8 fp_ = *(const bf16x8*)&sP[(w * 32 + mi * 16 + l15) * 40 + quad * 8];
            #pragma unroll
            for (int ni = 0; ni < 4; ni++)
                pacc[mi][ni] = MFMA_BF16(fp_, fv[ni], pacc[mi][ni]);
        }
    }

    // denominator column: f=50 -> ni=3, lane&15==2
    if (l15 == 2) {
        #pragma unroll
        for (int mi = 0; mi < 2; mi++)
            #pragma unroll
            for (int r = 0; r < 4; r++)
                sDen[w * 32 + mi * 16 + quad * 4 + r] = pacc[mi][3][r];
    }
    __syncthreads();

    #pragma unroll
    for (int mi = 0; mi < 2; mi++)
        #pragma unroll
        for (int ni = 0; ni < 4; ni++) {
            int f = ni * 16 + l15;
            if (f < F_) {
                #pragma unroll
                for (int r = 0; r < 4; r++) {
                    int yl = w * 32 + mi * 16 + quad * 4 + r;
                    int y = y0 + yl;
                    if (y < Y_)
                        m4t[((size_t)b * Y_ + y) * F_ + f] = pacc[mi][ni][r] / sDen[yl];
                }
            }
        }
}

// ---------------------------------------------------------------- support + y4t
// Bt : bf16 [KT_][NT_][32]  (z-tiled, n = b*50+g;  pads pre-zeroed by memset)
__global__ __launch_bounds__(256) void k3_support(
    const float* __restrict__ m4t, const float* __restrict__ gcn_w,
    const float* __restrict__ f4t_w, const float* __restrict__ f4t_b,
    u16* __restrict__ Bt, float* __restrict__ y4t_out)
{
    __shared__ float sW[50 * 52];   // gcn_w^T : [g][f], rows padded 52
    const int tid = threadIdx.x;
    for (int i = tid; i < 50 * 52; i += 256) {
        int g = i / 52, f = i - g * 52;
        sW[i] = (f < F_) ? gcn_w[f * F_ + g] : 0.f;
    }
    __syncthreads();

    const int b = blockIdx.y;
    const int y = blockIdx.x * 256 + tid;
    if (y >= Y_) return;

    float2 m[25];
    const float* mrow = m4t + ((size_t)b * Y_ + y) * F_;
    #pragma unroll
    for (int i = 0; i < 25; i++) m[i] = *(const float2*)(mrow + 2 * i);

    const int kt = y >> 5, zo = y & 31;
    u16* brow = Bt + (size_t)kt * (NT_ * 32) + (size_t)(b * F_) * 32 + zo;
    for (int g = 0; g < F_; g++) {
        float s = 0.f;
        const float* wr = sW + g * 52;
        #pragma unroll
        for (int i = 0; i < 25; i++) {
            float2 wv = *(const float2*)(wr + 2 * i);
            s += m[i].x * wv.x + m[i].y * wv.y;
        }
        brow[g * 32] = f2bf(s);
    }

    const float* tw = f4t_w + (size_t)y * F_;
    float acc = f4t_b[y];
    #pragma unroll
    for (int i = 0; i < 25; i++) {
        float2 wv = *(const float2*)(tw + 2 * i);
        acc += m[i].x * wv.x + m[i].y * wv.y;
    }
    y4t_out[(size_t)b * Y_ + y] = acc;
}

// ---------------------------------------------------------------- adj GEMM (the big one)
// out_part : fp32 [4][Y_][400]
__global__ __launch_bounds__(512) void k4_gemm(
    const float* __restrict__ adj, const u16* __restrict__ Bt,
    float* __restrict__ outp)
{
    __shared__ u16 sA[128 * 40];   // adj tile  [m][k], rows padded 40 (80B, 16B-aligned)
    __shared__ u16 sB[NT_ * 40];   // support tile [n][k]
    const int tid  = threadIdx.x;
    const int m0   = blockIdx.x * 128;
    const int kp   = blockIdx.y;
    const int w    = tid >> 6;
    const int lane = tid & 63;
    const int l15  = lane & 15;
    const int quad = lane >> 4;
    const int wm   = w & 3;    // M sub-block (0..3) -> rows wm*32..+32
    const int wn   = w >> 1 >> 1;  // N half (0..1) -> cols wn*208..+208

    const f32x4 fz = {0.f, 0.f, 0.f, 0.f};
    f32x4 acc[2][13];
    #pragma unroll
    for (int mi = 0; mi < 2; mi++)
        #pragma unroll
        for (int ni = 0; ni < 13; ni++) acc[mi][ni] = fz;

    for (int it = 0; it < 70; it++) {
        const int kt = kp * 70 + it;
        const int k0 = kt * 32;
        __syncthreads();
        {   // stage A: 128 rows x 32 cols fp32 -> bf16
            int r = tid >> 2, q = tid & 3;
            int y = m0 + r;
            int c0 = k0 + q * 8;
            float v[8];
            if (y < Y_ && c0 + 7 < Y_) {
                const float* src = adj + (size_t)y * Y_ + c0;
                float2 a0 = *(const float2*)(src);
                float2 a1 = *(const float2*)(src + 2);
                float2 a2 = *(const float2*)(src + 4);
                float2 a3 = *(const float2*)(src + 6);
                v[0] = a0.x; v[1] = a0.y; v[2] = a1.x; v[3] = a1.y;
                v[4] = a2.x; v[5] = a2.y; v[6] = a3.x; v[7] = a3.y;
            } else if (y < Y_) {
                #pragma unroll
                for (int j = 0; j < 8; j++)
                    v[j] = (c0 + j < Y_) ? adj[(size_t)y * Y_ + c0 + j] : 0.f;
            } else {
                #pragma unroll
                for (int j = 0; j < 8; j++) v[j] = 0.f;
            }
            u16x8 vv;
            #pragma unroll
            for (int j = 0; j < 8; j++) vv[j] = f2bf(v[j]);
            *(u16x8*)&sA[r * 40 + q * 8] = vv;
        }
        {   // stage B: contiguous 26624B tile -> padded rows
            const u16* bsrc = Bt + (size_t)kt * (NT_ * 32);
            #pragma unroll
            for (int it2 = 0; it2 < 4; it2++) {
                int idx = it2 * 512 + tid;
                if (idx < (NT_ * 32) / 8) {
                    u16x8 v = *(const u16x8*)&bsrc[idx * 8];
                    int n = idx >> 2, ko = (idx & 3) * 8;
                    *(u16x8*)&sB[n * 40 + ko] = v;
                }
            }
        }
        __syncthreads();

        bf16x8 fa_[2];
        #pragma unroll
        for (int mi = 0; mi < 2; mi++)
            fa_[mi] = *(const bf16x8*)&sA[(wm * 32 + mi * 16 + l15) * 40 + quad * 8];
        #pragma unroll
        for (int ni = 0; ni < 13; ni++) {
            bf16x8 fb = *(const bf16x8*)&sB[(wn * 208 + ni * 16 + l15) * 40 + quad * 8];
            acc[0][ni] = MFMA_BF16(fa_[0], fb, acc[0][ni]);
            acc[1][ni] = MFMA_BF16(fa_[1], fb, acc[1][ni]);
        }
    }

    float* dst = outp + (size_t)kp * Y_ * 400;
    #pragma unroll
    for (int mi = 0; mi < 2; mi++)
        #pragma unroll
        for (int ni = 0; ni < 13; ni++) {
            int n = wn * 208 + ni * 16 + l15;
            if (n < 400) {
                #pragma unroll
                for (int r = 0; r < 4; r++) {
                    int y = m0 + wm * 32 + mi * 16 + quad * 4 + r;
                    if (y < Y_) dst[(size_t)y * 400 + n] = acc[mi][ni][r];
                }
            }
        }
}

// ---------------------------------------------------------------- final y4
__global__ __launch_bounds__(256) void k5_final(
    const float* __restrict__ outp, const float* __restrict__ m4t,
    const float* __restrict__ gcn_b, const float* __restrict__ f4_w,
    const float* __restrict__ f4_b, float* __restrict__ y4_out)
{
    const int b = blockIdx.y;
    const int y = blockIdx.x * 256 + threadIdx.x;
    if (y >= Y_) return;

    const size_t PS = (size_t)Y_ * 400;
    const float* p0 = outp + (size_t)y * 400 + b * F_;
    const float* fw = f4_w + (size_t)y * 100;
    const float* mrow = m4t + ((size_t)b * Y_ + y) * F_;

    float acc = f4_b[y];
    #pragma unroll
    for (int i = 0; i < 25; i++) {
        float2 mv = *(const float2*)(mrow + 2 * i);
        float2 wv = *(const float2*)(fw + 2 * i);
        acc += mv.x * wv.x + mv.y * wv.y;
    }
    #pragma unroll
    for (int i = 0; i < 25; i++) {
        float sx = 0.f, sy = 0.f;
        #pragma unroll
        for (int kp = 0; kp < 4; kp++) {
            float2 v = *(const float2*)(p0 + kp * PS + 2 * i);
            sx += v.x; sy += v.y;
        }
        float2 gb = *(const float2*)(gcn_b + 2 * i);
        sx += gb.x; sy += gb.y;
        sx = sx > 0.f ? sx : 0.2f * sx;   // leaky_relu
        sy = sy > 0.f ? sy : 0.2f * sy;
        float2 wv = *(const float2*)(fw + 50 + 2 * i);
        acc += sx * wv.x + sy * wv.y;
    }
    y4_out[(size_t)b * Y_ + y] = acc;
}

// ---------------------------------------------------------------- launch
extern "C" void kernel_launch(void* const* d_in, const int* in_sizes, int n_in,
                              void* d_out, int out_size, void* d_ws, size_t ws_size,
                              hipStream_t stream) {
    const int*   x       = (const int*)d_in[0];
    const float* embed_w = (const float*)d_in[2];
    const float* conv_w  = (const float*)d_in[3];
    const float* conv_b  = (const float*)d_in[4];
    const float* U4_w    = (const float*)d_in[5];
    const float* gcn_w   = (const float*)d_in[6];
    const float* gcn_b   = (const float*)d_in[7];
    const float* adj     = (const float*)d_in[8];
    const float* f4t_w   = (const float*)d_in[9];
    const float* f4t_b   = (const float*)d_in[10];
    const float* f4_w    = (const float*)d_in[11];
    const float* f4_b    = (const float*)d_in[12];
    float* out = (float*)d_out;

    char* ws = (char*)d_ws;
    const size_t SZ_WT  = 180224;                            // 9*50*100*4 rounded
    const size_t SZ_HP  = (size_t)B_ * LP * 64 * 2;          // 2,588,672
    const size_t SZ_BT  = (size_t)KT_ * NT_ * 32 * 2;        // 7,454,720
    const size_t SZ_M4T = (size_t)B_ * Y_ * F_ * 4;          // 14,275,200
    int*   flag = (int*)ws;
    float* wT   = (float*)(ws + 16);
    u16*   hp   = (u16*)(ws + 16 + SZ_WT);
    u16*   hpT  = (u16*)(ws + 16 + SZ_WT + SZ_HP);
    u16*   Bt   = (u16*)(ws + 16 + SZ_WT + 2 * SZ_HP);
    float* m4t  = (float*)(ws + 16 + SZ_WT + 2 * SZ_HP + SZ_BT);
    float* outp = (float*)(ws + 16 + SZ_WT + 2 * SZ_HP + SZ_BT + SZ_M4T);

    k0_prep<<<9, 256, 0, stream>>>(x, conv_w, flag, wT);
    k1_conv<<<dim3(40, 8), 256, 0, stream>>>(x, flag, embed_w, wT, conv_b, hp, hpT);
    hipMemsetAsync(Bt, 0, SZ_BT, stream);
    k2_attn<<<dim3(70, 8), 256, 0, stream>>>(U4_w, hp, hpT, m4t);
    k3_support<<<dim3(35, 8), 256, 0, stream>>>(m4t, gcn_w, f4t_w, f4t_b, Bt, out);
    k4_gemm<<<dim3(70, 4), 512, 0, stream>>>(adj, Bt, outp);
    k5_final<<<dim3(35, 8), 256, 0, stream>>>(outp, m4t, gcn_b, f4_w, f4_b,
                                              out + (size_t)B_ * Y_);
}

// Round 3
// 1060.533 us; speedup vs baseline: 1.2655x; 1.0507x over previous
//
#include <hip/hip_runtime.h>

typedef unsigned short u16;
typedef short bf16x8 __attribute__((ext_vector_type(8)));   // MFMA A/B frag (8 bf16)
typedef float f32x4  __attribute__((ext_vector_type(4)));   // MFMA C/D frag
typedef u16   u16x8  __attribute__((ext_vector_type(8)));   // 16B vector ld/st

#define MFMA_BF16(a, b, c) __builtin_amdgcn_mfma_f32_16x16x32_bf16((a), (b), (c), 0, 0, 0)

#define B_  8
#define L_  2500
#define LP  2528          // L padded to 79*32
#define E_  100
#define F_  50
#define Y_  8922
#define YP  8960          // Y padded to 280*32
#define KT_ 280           // K tiles of 32 over YP
#define NT_ 416           // N = B*F = 400 padded to 26*16
#define KP_ 8             // K-split for adj GEMM (280/8 = 35 tiles per part)

__device__ __forceinline__ u16 f2bf(float f) {
    unsigned int x = __float_as_uint(f);
    unsigned int r = x + 0x7fffu + ((x >> 16) & 1u);   // RNE
    return (u16)(r >> 16);
}

// ---------------------------------------------------------------- prep
__global__ __launch_bounds__(256) void k0_prep(
    const int* __restrict__ x, const float* __restrict__ conv_w,
    int* __restrict__ flag, float* __restrict__ wT)
{
    const int k = blockIdx.x;           // 0..8
    const int tid = threadIdx.x;
    if (k == 0 && tid == 0) {
        int nz = 0;
        #pragma unroll
        for (int i = 0; i < 32; i++) nz |= x[2 * i + 1];
        *flag = (nz == 0) ? 1 : 0;      // all-high-words-zero => int64 buffer
    }
    for (int j = tid; j < 5000; j += 256)           // j = f*100 + e
        wT[k * 5000 + j] = conv_w[j * 9 + k];
}

// ---------------------------------------------------------------- conv (fp32, LDS-staged weights)
__global__ __launch_bounds__(256) void k1_conv(
    const int* __restrict__ x, const int* __restrict__ flag,
    const float* __restrict__ embed_w, const float* __restrict__ wT,
    const float* __restrict__ conv_b,
    u16* __restrict__ hp, u16* __restrict__ hpT)
{
    __shared__ float sEmb[72 * 104];   // 72 rows (64 + 8 halo), stride 104
    __shared__ float sW[50 * 104];     // per-k weight slice [f][e], stride 104
    __shared__ int   sId[72];
    const int tid = threadIdx.x;
    const int b  = blockIdx.y;
    const int l0 = blockIdx.x * 64;
    const int is64 = *flag;

    if (tid < 72) {
        int l = l0 - 4 + tid;
        int id = -1;
        if (l >= 0 && l < L_) id = is64 ? x[(b * L_ + l) * 2] : x[b * L_ + l];
        sId[tid] = id;
    }
    __syncthreads();
    for (int i = tid; i < 72 * 25; i += 256) {       // float4 granules
        int r = i / 25, e4 = i - r * 25;
        int id = sId[r];
        float4 v = make_float4(0.f, 0.f, 0.f, 0.f);
        if (id >= 0) v = *(const float4*)&embed_w[(size_t)id * 100 + e4 * 4];
        *(float4*)&sEmb[r * 104 + e4 * 4] = v;
    }

    const int li = tid & 63;
    const int fg = __builtin_amdgcn_readfirstlane(tid >> 6);   // wave-uniform f-group 0..3

    float acc[13];
    #pragma unroll
    for (int i = 0; i < 13; i++) { int f = fg + 4 * i; acc[i] = (f < F_) ? conv_b[f] : 0.f; }

    for (int k = 0; k < 9; k++) {
        __syncthreads();
        for (int i = tid; i < 1250; i += 256) {      // stage wT[k] : 50 f x 25 float4
            int f = i / 25, e4 = i - f * 25;
            *(float4*)&sW[f * 104 + e4 * 4] = *(const float4*)&wT[k * 5000 + f * 100 + e4 * 4];
        }
        __syncthreads();
        for (int e4 = 0; e4 < 25; e4++) {
            float4 h = *(const float4*)&sEmb[(li + k) * 104 + e4 * 4];
            #pragma unroll
            for (int i = 0; i < 13; i++) {
                int f = fg + 4 * i;
                if (f < F_) {
                    float4 w = *(const float4*)&sW[f * 104 + e4 * 4];   // uniform -> LDS broadcast
                    acc[i] += h.x * w.x + h.y * w.y + h.z * w.z + h.w * w.w;
                }
            }
        }
    }

    int l = l0 + li;
    if (l < LP) {
        bool valid = (l < L_);
        #pragma unroll
        for (int i = 0; i < 13; i++) {
            int f = fg + 4 * i;
            if (f < F_) {
                u16 hv = 0;
                if (valid) {
                    float e2 = __expf(2.f * acc[i]);
                    hv = f2bf((e2 - 1.f) / (e2 + 1.f));   // tanh
                }
                hp [((size_t)b * LP + l) * 64 + f] = hv;
                hpT[((size_t)b * 64 + f) * LP + l] = hv;
            }
        }
        #pragma unroll
        for (int j = 0; j < 4; j++) {
            int f = 50 + fg + 4 * j;
            if (f < 64) {
                hp [((size_t)b * LP + l) * 64 + f] = 0;
                hpT[((size_t)b * 64 + f) * LP + l] = (f == 50 && valid) ? f2bf(1.f) : (u16)0;
            }
        }
    }
}

// ---------------------------------------------------------------- flash attention (reg-prefetch pipelined)
__global__ __launch_bounds__(256) void k2_attn(
    const float* __restrict__ U4_w,
    const u16* __restrict__ hp, const u16* __restrict__ hpT,
    float* __restrict__ m4t)
{
    __shared__ u16  sU4[128 * 72];   // [y][f] f-contig, rows padded 72
    __shared__ u16  sHp[32 * 72];    // [l][f] f-contig (S-GEMM B)
    __shared__ u16  sHt[64 * 40];    // [f][l] l-contig (PV B), rows padded 40
    __shared__ u16  sP [128 * 40];   // [y][l] l-contig (PV A)
    __shared__ float sDen[128];

    const int tid  = threadIdx.x;
    const int b    = blockIdx.y;
    const int y0   = blockIdx.x * 128;
    const int w    = tid >> 6;
    const int lane = tid & 63;
    const int l15  = lane & 15;
    const int quad = lane >> 4;

    for (int i = tid; i < 128 * 72; i += 256) {
        int r = i / 72, c = i - r * 72;
        float v = 0.f;
        int y = y0 + r;
        if (c < F_ && y < Y_) v = U4_w[y * F_ + c];
        sU4[i] = f2bf(v);
    }
    __syncthreads();

    bf16x8 fa[2][2];   // hoisted U4 A-frags
    #pragma unroll
    for (int mi = 0; mi < 2; mi++)
        #pragma unroll
        for (int ks = 0; ks < 2; ks++)
            fa[mi][ks] = *(const bf16x8*)&sU4[(w * 32 + mi * 16 + l15) * 72 + ks * 32 + quad * 8];

    const f32x4 fz = {0.f, 0.f, 0.f, 0.f};
    f32x4 pacc[2][4];
    #pragma unroll
    for (int mi = 0; mi < 2; mi++)
        #pragma unroll
        for (int ni = 0; ni < 4; ni++) pacc[mi][ni] = fz;

    // staging coords + prefetch regs
    const int rr = tid >> 3, seg = tid & 7;      // hp tile [32][64]
    const int fr = tid >> 2, s2 = tid & 3;       // hpT tile [64][32]
    u16x8 pv, pv2;
    {
        pv  = *(const u16x8*)&hp [((size_t)b * LP + rr) * 64 + seg * 8];
        pv2 = *(const u16x8*)&hpT[((size_t)b * 64 + fr) * LP + s2 * 8];
    }

    for (int lt = 0; lt < 79; lt++) {
        const int l0 = lt * 32;
        __syncthreads();
        *(u16x8*)&sHp[rr * 72 + seg * 8] = pv;
        *(u16x8*)&sHt[fr * 40 + s2 * 8] = pv2;
        if (lt + 1 < 79) {   // prefetch next tile; latency hidden under S+PV compute
            const int ln = l0 + 32;
            pv  = *(const u16x8*)&hp [((size_t)b * LP + ln + rr) * 64 + seg * 8];
            pv2 = *(const u16x8*)&hpT[((size_t)b * 64 + fr) * LP + ln + s2 * 8];
        }
        __syncthreads();

        // S = U4p [y×64f] · hp^T [64f×l]
        f32x4 sacc[2][2];
        #pragma unroll
        for (int mi = 0; mi < 2; mi++)
            #pragma unroll
            for (int ni = 0; ni < 2; ni++) sacc[mi][ni] = fz;
        #pragma unroll
        for (int ks = 0; ks < 2; ks++) {
            #pragma unroll
            for (int ni = 0; ni < 2; ni++) {
                bf16x8 fb = *(const bf16x8*)&sHp[(ni * 16 + l15) * 72 + ks * 32 + quad * 8];
                #pragma unroll
                for (int mi = 0; mi < 2; mi++)
                    sacc[mi][ni] = MFMA_BF16(fa[mi][ks], fb, sacc[mi][ni]);
            }
        }
        // P = exp(S), write to LDS in A-layout
        #pragma unroll
        for (int mi = 0; mi < 2; mi++)
            #pragma unroll
            for (int ni = 0; ni < 2; ni++) {
                int lcol = ni * 16 + l15;
                bool lv = (l0 + lcol) < L_;
                #pragma unroll
                for (int r = 0; r < 4; r++) {
                    float p = lv ? __expf(sacc[mi][ni][r]) : 0.f;
                    sP[(w * 32 + mi * 16 + quad * 4 + r) * 40 + lcol] = f2bf(p);
                }
            }
        __syncthreads();

        // O += P [y×32l] · hp [32l×64f]
        bf16x8 fv[4];
        #pragma unroll
        for (int ni = 0; ni < 4; ni++)
            fv[ni] = *(const bf16x8*)&sHt[(ni * 16 + l15) * 40 + quad * 8];
        #pragma unroll
        for (int mi = 0; mi < 2; mi++) {
            bf16x8 fp_ = *(const bf16x8*)&sP[(w * 32 + mi * 16 + l15) * 40 + quad * 8];
            #pragma unroll
            for (int ni = 0; ni < 4; ni++)
                pacc[mi][ni] = MFMA_BF16(fp_, fv[ni], pacc[mi][ni]);
        }
    }

    // denominator column: f=50 -> ni=3, lane&15==2
    if (l15 == 2) {
        #pragma unroll
        for (int mi = 0; mi < 2; mi++)
            #pragma unroll
            for (int r = 0; r < 4; r++)
                sDen[w * 32 + mi * 16 + quad * 4 + r] = pacc[mi][3][r];
    }
    __syncthreads();

    #pragma unroll
    for (int mi = 0; mi < 2; mi++)
        #pragma unroll
        for (int ni = 0; ni < 4; ni++) {
            int f = ni * 16 + l15;
            if (f < F_) {
                #pragma unroll
                for (int r = 0; r < 4; r++) {
                    int yl = w * 32 + mi * 16 + quad * 4 + r;
                    int y = y0 + yl;
                    if (y < Y_)
                        m4t[((size_t)b * Y_ + y) * F_ + f] = pacc[mi][ni][r] / sDen[yl];
                }
            }
        }
}

// ---------------------------------------------------------------- support + y4t
__global__ __launch_bounds__(256) void k3_support(
    const float* __restrict__ m4t, const float* __restrict__ gcn_w,
    const float* __restrict__ f4t_w, const float* __restrict__ f4t_b,
    u16* __restrict__ Bt, float* __restrict__ y4t_out)
{
    __shared__ float sW[50 * 52];   // gcn_w^T : [g][f], rows padded 52
    const int tid = threadIdx.x;
    for (int i = tid; i < 50 * 52; i += 256) {
        int g = i / 52, f = i - g * 52;
        sW[i] = (f < F_) ? gcn_w[f * F_ + g] : 0.f;
    }
    __syncthreads();

    const int b = blockIdx.y;
    const int y = blockIdx.x * 256 + tid;
    if (y >= Y_) return;

    float2 m[25];
    const float* mrow = m4t + ((size_t)b * Y_ + y) * F_;
    #pragma unroll
    for (int i = 0; i < 25; i++) m[i] = *(const float2*)(mrow + 2 * i);

    const int kt = y >> 5, zo = y & 31;
    u16* brow = Bt + (size_t)kt * (NT_ * 32) + (size_t)(b * F_) * 32 + zo;
    for (int g = 0; g < F_; g++) {
        float s = 0.f;
        const float* wr = sW + g * 52;
        #pragma unroll
        for (int i = 0; i < 25; i++) {
            float2 wv = *(const float2*)(wr + 2 * i);
            s += m[i].x * wv.x + m[i].y * wv.y;
        }
        brow[g * 32] = f2bf(s);
    }

    const float* tw = f4t_w + (size_t)y * F_;
    float acc = f4t_b[y];
    #pragma unroll
    for (int i = 0; i < 25; i++) {
        float2 wv = *(const float2*)(tw + 2 * i);
        acc += m[i].x * wv.x + m[i].y * wv.y;
    }
    y4t_out[(size_t)b * Y_ + y] = acc;
}

// ---------------------------------------------------------------- adj GEMM
// M-tile 64, N = 416 (full), K-split 8 -> 140x8 = 1120 blocks (~4.4/CU),
// register-prefetch pipeline hides global latency under MFMA phase.
// out_part : fp32 [KP_][Y_][400]
__global__ __launch_bounds__(256) void k4_gemm(
    const float* __restrict__ adj, const u16* __restrict__ Bt,
    float* __restrict__ outp)
{
    __shared__ u16 sA[64 * 40];    // adj tile  [m][k], rows padded 40
    __shared__ u16 sB[NT_ * 40];   // support tile [n][k]
    const int tid  = threadIdx.x;
    const int m0   = blockIdx.x * 64;
    const int kp   = blockIdx.y;
    const int w    = tid >> 6;
    const int lane = tid & 63;
    const int l15  = lane & 15;
    const int quad = lane >> 4;
    const int wm   = w & 1;        // M sub-block (0..1) -> rows wm*32..+32
    const int wn   = w >> 1;       // N half (0..1) -> cols wn*208..+208

    const int r = tid >> 2, q = tid & 3;    // A staging coords: row r, 8-col chunk q
    const int yA = m0 + r;
    const float* arow = adj + (size_t)yA * Y_;

    const f32x4 fz = {0.f, 0.f, 0.f, 0.f};
    f32x4 acc[2][13];
    #pragma unroll
    for (int mi = 0; mi < 2; mi++)
        #pragma unroll
        for (int ni = 0; ni < 13; ni++) acc[mi][ni] = fz;

    float av[8];
    u16x8 bv[7];
    const int kt0 = kp * 35;

    auto loadA = [&](int kt) {
        int c0 = kt * 32 + q * 8;
        if (yA < Y_ && c0 + 7 < Y_) {
            #pragma unroll
            for (int j = 0; j < 4; j++) {   // float2: rows are only 8B-aligned (Y_*4 % 16 == 8)
                float2 t = *(const float2*)(arow + c0 + 2 * j);
                av[2 * j] = t.x; av[2 * j + 1] = t.y;
            }
        } else if (yA < Y_) {
            #pragma unroll
            for (int j = 0; j < 8; j++) av[j] = (c0 + j < Y_) ? arow[c0 + j] : 0.f;
        } else {
            #pragma unroll
            for (int j = 0; j < 8; j++) av[j] = 0.f;
        }
    };
    auto loadB = [&](int kt) {
        const u16* bsrc = Bt + (size_t)kt * (NT_ * 32);
        #pragma unroll
        for (int j = 0; j < 6; j++) bv[j] = *(const u16x8*)&bsrc[(j * 256 + tid) * 8];
        if (tid < 128) bv[6] = *(const u16x8*)&bsrc[(1536 + tid) * 8];
    };

    loadA(kt0); loadB(kt0);

    for (int it = 0; it < 35; it++) {
        __syncthreads();
        {   // commit prefetched regs to LDS
            u16x8 vv;
            #pragma unroll
            for (int j = 0; j < 8; j++) vv[j] = f2bf(av[j]);
            *(u16x8*)&sA[r * 40 + q * 8] = vv;
            #pragma unroll
            for (int j = 0; j < 6; j++) {
                int idx = j * 256 + tid;
                *(u16x8*)&sB[(idx >> 2) * 40 + (idx & 3) * 8] = bv[j];
            }
            if (tid < 128) {
                int idx = 1536 + tid;
                *(u16x8*)&sB[(idx >> 2) * 40 + (idx & 3) * 8] = bv[6];
            }
        }
        if (it + 1 < 35) { loadA(kt0 + it + 1); loadB(kt0 + it + 1); }   // hidden under MFMA
        __syncthreads();

        bf16x8 fa0 = *(const bf16x8*)&sA[(wm * 32 + l15) * 40 + quad * 8];
        bf16x8 fa1 = *(const bf16x8*)&sA[(wm * 32 + 16 + l15) * 40 + quad * 8];
        #pragma unroll
        for (int ni = 0; ni < 13; ni++) {
            bf16x8 fb = *(const bf16x8*)&sB[(wn * 208 + ni * 16 + l15) * 40 + quad * 8];
            acc[0][ni] = MFMA_BF16(fa0, fb, acc[0][ni]);
            acc[1][ni] = MFMA_BF16(fa1, fb, acc[1][ni]);
        }
    }

    float* dst = outp + (size_t)kp * Y_ * 400;
    #pragma unroll
    for (int mi = 0; mi < 2; mi++)
        #pragma unroll
        for (int ni = 0; ni < 13; ni++) {
            int n = wn * 208 + ni * 16 + l15;
            if (n < 400) {
                #pragma unroll
                for (int r4 = 0; r4 < 4; r4++) {
                    int y = m0 + wm * 32 + mi * 16 + quad * 4 + r4;
                    if (y < Y_) dst[(size_t)y * 400 + n] = acc[mi][ni][r4];
                }
            }
        }
}

// ---------------------------------------------------------------- final y4
__global__ __launch_bounds__(256) void k5_final(
    const float* __restrict__ outp, const float* __restrict__ m4t,
    const float* __restrict__ gcn_b, const float* __restrict__ f4_w,
    const float* __restrict__ f4_b, float* __restrict__ y4_out)
{
    const int b = blockIdx.y;
    const int y = blockIdx.x * 256 + threadIdx.x;
    if (y >= Y_) return;

    const size_t PS = (size_t)Y_ * 400;
    const float* p0 = outp + (size_t)y * 400 + b * F_;
    const float* fw = f4_w + (size_t)y * 100;
    const float* mrow = m4t + ((size_t)b * Y_ + y) * F_;

    float acc = f4_b[y];
    #pragma unroll
    for (int i = 0; i < 25; i++) {
        float2 mv = *(const float2*)(mrow + 2 * i);
        float2 wv = *(const float2*)(fw + 2 * i);
        acc += mv.x * wv.x + mv.y * wv.y;
    }
    #pragma unroll
    for (int i = 0; i < 25; i++) {
        float sx = 0.f, sy = 0.f;
        #pragma unroll
        for (int kp = 0; kp < KP_; kp++) {
            float2 v = *(const float2*)(p0 + kp * PS + 2 * i);
            sx += v.x; sy += v.y;
        }
        float2 gb = *(const float2*)(gcn_b + 2 * i);
        sx += gb.x; sy += gb.y;
        sx = sx > 0.f ? sx : 0.2f * sx;   // leaky_relu
        sy = sy > 0.f ? sy : 0.2f * sy;
        float2 wv = *(const float2*)(fw + 50 + 2 * i);
        acc += sx * wv.x + sy * wv.y;
    }
    y4_out[(size_t)b * Y_ + y] = acc;
}

// ---------------------------------------------------------------- launch
extern "C" void kernel_launch(void* const* d_in, const int* in_sizes, int n_in,
                              void* d_out, int out_size, void* d_ws, size_t ws_size,
                              hipStream_t stream) {
    const int*   x       = (const int*)d_in[0];
    const float* embed_w = (const float*)d_in[2];
    const float* conv_w  = (const float*)d_in[3];
    const float* conv_b  = (const float*)d_in[4];
    const float* U4_w    = (const float*)d_in[5];
    const float* gcn_w   = (const float*)d_in[6];
    const float* gcn_b   = (const float*)d_in[7];
    const float* adj     = (const float*)d_in[8];
    const float* f4t_w   = (const float*)d_in[9];
    const float* f4t_b   = (const float*)d_in[10];
    const float* f4_w    = (const float*)d_in[11];
    const float* f4_b    = (const float*)d_in[12];
    float* out = (float*)d_out;

    char* ws = (char*)d_ws;
    const size_t SZ_WT  = 180224;                            // 9*50*100*4 rounded
    const size_t SZ_HP  = (size_t)B_ * LP * 64 * 2;          // 2,588,672
    const size_t SZ_BT  = (size_t)KT_ * NT_ * 32 * 2;        // 7,454,720
    const size_t SZ_M4T = (size_t)B_ * Y_ * F_ * 4;          // 14,275,200
    int*   flag = (int*)ws;
    float* wT   = (float*)(ws + 16);
    u16*   hp   = (u16*)(ws + 16 + SZ_WT);
    u16*   hpT  = (u16*)(ws + 16 + SZ_WT + SZ_HP);
    u16*   Bt   = (u16*)(ws + 16 + SZ_WT + 2 * SZ_HP);
    float* m4t  = (float*)(ws + 16 + SZ_WT + 2 * SZ_HP + SZ_BT);
    float* outp = (float*)(ws + 16 + SZ_WT + 2 * SZ_HP + SZ_BT + SZ_M4T);  // KP_*Y*400*4 = 114 MB

    k0_prep<<<9, 256, 0, stream>>>(x, conv_w, flag, wT);
    k1_conv<<<dim3(40, 8), 256, 0, stream>>>(x, flag, embed_w, wT, conv_b, hp, hpT);
    hipMemsetAsync(Bt, 0, SZ_BT, stream);
    k2_attn<<<dim3(70, 8), 256, 0, stream>>>(U4_w, hp, hpT, m4t);
    k3_support<<<dim3(35, 8), 256, 0, stream>>>(m4t, gcn_w, f4t_w, f4t_b, Bt, out);
    k4_gemm<<<dim3(140, KP_), 256, 0, stream>>>(adj, Bt, outp);
    k5_final<<<dim3(35, 8), 256, 0, stream>>>(outp, m4t, gcn_b, f4_w, f4_b,
                                              out + (size_t)B_ * Y_);
}